// Round 1
// baseline (3602.766 us; speedup 1.0000x reference)
//
#include <hip/hip_runtime.h>

// Problem constants
constexpr int B = 2, S = 2048, D = 1024, H = 16, HD = 64;
constexpr size_t BSD = (size_t)B * S * D;      // 4,194,304 elements
constexpr float SCALE = 0.125f;                 // 1/sqrt(HD)
constexpr float EPS = 1e-5f;

typedef unsigned short u16;
typedef __attribute__((ext_vector_type(8))) short bf16x8;   // 8 bf16 = 4 VGPRs
typedef __attribute__((ext_vector_type(4))) float f32x4;    // MFMA acc frag

__device__ __forceinline__ u16 f2bf(float f) {
    union { float f; unsigned u; } x; x.f = f;
    unsigned r = x.u + 0x7FFFu + ((x.u >> 16) & 1u);  // RNE
    return (u16)(r >> 16);
}

// ---------------------------------------------------------------------------
// fp32 -> bf16 elementwise cast (4 elems/thread)
// ---------------------------------------------------------------------------
__global__ void cast_bf16_kernel(const float* __restrict__ in, u16* __restrict__ out, int n4) {
    int i = blockIdx.x * blockDim.x + threadIdx.x;
    if (i < n4) {
        float4 f = ((const float4*)in)[i];
        ushort4 o;
        o.x = f2bf(f.x); o.y = f2bf(f.y); o.z = f2bf(f.z); o.w = f2bf(f.w);
        ((ushort4*)out)[i] = o;
    }
}

// ---------------------------------------------------------------------------
// W[k][n] fp32 -> Wt[n][k] bf16 (32x32 LDS tiles)
// ---------------------------------------------------------------------------
__global__ void wtrans_kernel(const float* __restrict__ W, u16* __restrict__ Wt) {
    __shared__ float t[32][33];
    int bx = blockIdx.x * 32;   // n block
    int by = blockIdx.y * 32;   // k block
    int tx = threadIdx.x & 31;
    int ty = threadIdx.x >> 5;  // 0..7
    #pragma unroll
    for (int i = 0; i < 32; i += 8)
        t[ty + i][tx] = W[(size_t)(by + ty + i) * D + bx + tx];
    __syncthreads();
    #pragma unroll
    for (int i = 0; i < 32; i += 8)
        Wt[(size_t)(bx + ty + i) * D + by + tx] = f2bf(t[tx][ty + i]);
}

// ---------------------------------------------------------------------------
// bf16 MFMA GEMM: C[M=4096][N=1024] = A[M][K=1024] * B[K][N]
//   A given as bf16; B given as Bt[n][k] bf16 (pre-transposed).
//   AMODE 0: A row-major [m][k]
//   AMODE 1: A is attn in [B][H][S][HD] layout, logical [m=(b,s)][k=(h,hd)]
//   CMODE 0: scatter fp32 to [B][H][S][HD]   (projections)
//   CMODE 1: row-major fp32 [m][n]           (output projection)
// Tile: 128x128 per block (256 thr = 4 waves, each 64x64), BK=32.
// ---------------------------------------------------------------------------
template <int AMODE, int CMODE>
__global__ __launch_bounds__(256) void gemm_bf16(const u16* __restrict__ A,
                                                 const u16* __restrict__ Bt,
                                                 float* __restrict__ C) {
    constexpr int K = 1024, N = 1024;
    constexpr int LDT = 40;  // 32 + 8 pad (keeps 16B alignment, breaks bank conflicts)
    __shared__ u16 As[128 * LDT];
    __shared__ u16 Bs[128 * LDT];

    const int tid = threadIdx.x;
    const int mbase = blockIdx.y * 128;
    const int nbase = blockIdx.x * 128;
    const int w = tid >> 6, lane = tid & 63;
    const int wrow = w >> 1, wcol = w & 1;
    const int quad = lane >> 4, l16 = lane & 15;

    const int sr = tid >> 1;            // staging row 0..127
    const int sc = (tid & 1) * 16;      // staging col 0 or 16

    f32x4 acc[4][4];
    #pragma unroll
    for (int i = 0; i < 4; ++i)
        #pragma unroll
        for (int j = 0; j < 4; ++j)
            acc[i][j] = (f32x4){0.f, 0.f, 0.f, 0.f};

    for (int k0 = 0; k0 < K; k0 += 32) {
        // global loads (2x16B per matrix per thread)
        const u16* abase;
        if (AMODE == 0) {
            abase = A + (size_t)(mbase + sr) * K + k0 + sc;
        } else {
            int mm = mbase + sr;
            int b = mm >> 11, s = mm & 2047;
            int kk = k0 + sc;
            int h = kk >> 6, off = kk & 63;
            abase = A + ((((size_t)b * H + h) * S + s) * HD + off);
        }
        uint4 av0 = *(const uint4*)abase;
        uint4 av1 = *(const uint4*)(abase + 8);
        const u16* bbase = Bt + (size_t)(nbase + sr) * K + k0 + sc;
        uint4 bv0 = *(const uint4*)bbase;
        uint4 bv1 = *(const uint4*)(bbase + 8);

        __syncthreads();  // previous iter's LDS reads done
        *(uint4*)&As[sr * LDT + sc] = av0;
        *(uint4*)&As[sr * LDT + sc + 8] = av1;
        *(uint4*)&Bs[sr * LDT + sc] = bv0;
        *(uint4*)&Bs[sr * LDT + sc + 8] = bv1;
        __syncthreads();

        bf16x8 af[4], bfr[4];
        #pragma unroll
        for (int i = 0; i < 4; ++i) {
            af[i] = *(const bf16x8*)&As[(wrow * 64 + i * 16 + l16) * LDT + quad * 8];
            bfr[i] = *(const bf16x8*)&Bs[(wcol * 64 + i * 16 + l16) * LDT + quad * 8];
        }
        #pragma unroll
        for (int i = 0; i < 4; ++i)
            #pragma unroll
            for (int j = 0; j < 4; ++j)
                acc[i][j] = __builtin_amdgcn_mfma_f32_16x16x32_bf16(af[i], bfr[j], acc[i][j], 0, 0, 0);
    }

    // epilogue: D layout col = lane&15 (n), row = quad*4 + reg (m)
    #pragma unroll
    for (int i = 0; i < 4; ++i) {
        int mrow0 = mbase + wrow * 64 + i * 16 + quad * 4;
        #pragma unroll
        for (int j = 0; j < 4; ++j) {
            int n = nbase + wcol * 64 + j * 16 + l16;
            #pragma unroll
            for (int r = 0; r < 4; ++r) {
                int mm = mrow0 + r;
                float val = acc[i][j][r];
                if (CMODE == 0) {
                    int b = mm >> 11, s = mm & 2047;
                    int h = n >> 6, hd = n & 63;
                    C[(((size_t)b * H + h) * S + s) * HD + hd] = val;
                } else {
                    C[(size_t)mm * N + n] = val;
                }
            }
        }
    }
}

// ---------------------------------------------------------------------------
// Causal attention, fp32 online softmax. One thread = one q row.
// Block 128 threads covers 128 consecutive rows of one (b,h).
// K/V row addresses are wave-uniform (broadcast-friendly).
// Writes attn as bf16 in [B][H][S][HD] for the output-proj GEMM.
// ---------------------------------------------------------------------------
__global__ __launch_bounds__(128) void attn_kernel(const float* __restrict__ Qh,
                                                   const float* __restrict__ Kh,
                                                   const float* __restrict__ Vh,
                                                   u16* __restrict__ attnb) {
    const int bh = blockIdx.y;                       // b*H + h
    const int row = blockIdx.x * 128 + threadIdx.x;  // q position
    const int jmax = blockIdx.x * 128 + 127;

    const float* Qr = Qh + ((size_t)bh * S + row) * HD;
    float q[HD];
    #pragma unroll
    for (int d = 0; d < HD; d += 4) {
        float4 f = *(const float4*)(Qr + d);
        q[d] = f.x; q[d + 1] = f.y; q[d + 2] = f.z; q[d + 3] = f.w;
    }

    float acc[HD];
    #pragma unroll
    for (int d = 0; d < HD; ++d) acc[d] = 0.f;
    float m = -INFINITY, l = 0.f;

    const float* Kb = Kh + (size_t)bh * S * HD;
    const float* Vb = Vh + (size_t)bh * S * HD;

    for (int j = 0; j <= jmax; ++j) {
        const float* Kr = Kb + (size_t)j * HD;
        const float* Vr = Vb + (size_t)j * HD;
        if (j <= row) {
            float d0 = 0.f, d1 = 0.f, d2 = 0.f, d3 = 0.f;
            #pragma unroll
            for (int d = 0; d < HD; d += 4) {
                float4 kv = *(const float4*)(Kr + d);
                d0 += q[d] * kv.x;
                d1 += q[d + 1] * kv.y;
                d2 += q[d + 2] * kv.z;
                d3 += q[d + 3] * kv.w;
            }
            float s = (d0 + d1) + (d2 + d3);
            s *= SCALE;
            float mn = fmaxf(m, s);
            float corr = __expf(m - mn);   // exp(-inf)=0 on first iter
            float p = __expf(s - mn);
            l = l * corr + p;
            m = mn;
            if (corr != 1.0f) {
                #pragma unroll
                for (int d = 0; d < HD; ++d) acc[d] *= corr;
            }
            #pragma unroll
            for (int d = 0; d < HD; d += 4) {
                float4 vv = *(const float4*)(Vr + d);
                acc[d]     += p * vv.x;
                acc[d + 1] += p * vv.y;
                acc[d + 2] += p * vv.z;
                acc[d + 3] += p * vv.w;
            }
        }
    }

    float inv = 1.0f / l;
    u16* orow = attnb + ((size_t)bh * S + row) * HD;
    #pragma unroll
    for (int d = 0; d < HD; d += 4) {
        ushort4 o;
        o.x = f2bf(acc[d] * inv);
        o.y = f2bf(acc[d + 1] * inv);
        o.z = f2bf(acc[d + 2] * inv);
        o.w = f2bf(acc[d + 3] * inv);
        *(ushort4*)(orow + d) = o;
    }
}

// ---------------------------------------------------------------------------
// LayerNorm(proj + q) * gamma + beta  -> out (fp32). One block per row.
// ---------------------------------------------------------------------------
__global__ __launch_bounds__(256) void ln_kernel(const float* __restrict__ proj,
                                                 const float* __restrict__ qin,
                                                 const float* __restrict__ gamma,
                                                 const float* __restrict__ beta,
                                                 float* __restrict__ out) {
    const int row = blockIdx.x;
    const int t = threadIdx.x;  // 256 threads, 4 elems each
    const float4 p = ((const float4*)(proj + (size_t)row * D))[t];
    const float4 qq = ((const float4*)(qin + (size_t)row * D))[t];
    float v0 = p.x + qq.x, v1 = p.y + qq.y, v2 = p.z + qq.z, v3 = p.w + qq.w;
    float sum = (v0 + v1) + (v2 + v3);
    float sq = v0 * v0 + v1 * v1 + v2 * v2 + v3 * v3;
    #pragma unroll
    for (int off = 32; off > 0; off >>= 1) {
        sum += __shfl_down(sum, off, 64);
        sq  += __shfl_down(sq, off, 64);
    }
    __shared__ float s1[4], s2[4];
    if ((t & 63) == 0) { s1[t >> 6] = sum; s2[t >> 6] = sq; }
    __syncthreads();
    sum = (s1[0] + s1[1]) + (s1[2] + s1[3]);
    sq  = (s2[0] + s2[1]) + (s2[2] + s2[3]);
    const float mu = sum * (1.0f / D);
    const float var = sq * (1.0f / D) - mu * mu;
    const float rstd = rsqrtf(var + EPS);
    const float4 g = ((const float4*)gamma)[t];
    const float4 b = ((const float4*)beta)[t];
    float4 o;
    o.x = (v0 - mu) * rstd * g.x + b.x;
    o.y = (v1 - mu) * rstd * g.y + b.y;
    o.z = (v2 - mu) * rstd * g.z + b.z;
    o.w = (v3 - mu) * rstd * g.w + b.w;
    ((float4*)(out + (size_t)row * D))[t] = o;
}

// ---------------------------------------------------------------------------
extern "C" void kernel_launch(void* const* d_in, const int* in_sizes, int n_in,
                              void* d_out, int out_size, void* d_ws, size_t ws_size,
                              hipStream_t stream) {
    const float* q  = (const float*)d_in[0];
    const float* k  = (const float*)d_in[1];
    const float* v  = (const float*)d_in[2];
    const float* wq = (const float*)d_in[3];
    const float* wk = (const float*)d_in[4];
    const float* wv = (const float*)d_in[5];
    const float* wo = (const float*)d_in[6];
    const float* gamma = (const float*)d_in[7];
    const float* beta  = (const float*)d_in[8];
    // d_in[9] = mask : deterministic causal mask, applied structurally.
    float* out = (float*)d_out;

    char* ws = (char*)d_ws;
    constexpr size_t SZ_BF = BSD * 2;              // 8.39 MB
    constexpr size_t SZ_W  = (size_t)D * D * 2;    // 2.10 MB
    constexpr size_t SZ_F  = BSD * 4;              // 16.78 MB
    u16* qb  = (u16*)(ws);
    u16* kb  = (u16*)(ws + SZ_BF);
    u16* vb  = (u16*)(ws + 2 * SZ_BF);
    u16* wqT = (u16*)(ws + 3 * SZ_BF);
    u16* wkT = (u16*)(ws + 3 * SZ_BF + SZ_W);
    u16* wvT = (u16*)(ws + 3 * SZ_BF + 2 * SZ_W);
    u16* woT = (u16*)(ws + 3 * SZ_BF + 3 * SZ_W);
    float* Qh = (float*)(ws + 3 * SZ_BF + 4 * SZ_W);
    float* Kh = (float*)(ws + 3 * SZ_BF + 4 * SZ_W + SZ_F);
    float* Vh = (float*)(ws + 3 * SZ_BF + 4 * SZ_W + 2 * SZ_F);
    u16* attnb = (u16*)(ws + 3 * SZ_BF + 4 * SZ_W + 3 * SZ_F);
    float* proj = (float*)(ws + 3 * SZ_BF + 4 * SZ_W + 3 * SZ_F + SZ_BF);

    const int n4 = (int)(BSD / 4);
    cast_bf16_kernel<<<n4 / 256, 256, 0, stream>>>(q, qb, n4);
    cast_bf16_kernel<<<n4 / 256, 256, 0, stream>>>(k, kb, n4);
    cast_bf16_kernel<<<n4 / 256, 256, 0, stream>>>(v, vb, n4);

    dim3 tg(32, 32);
    wtrans_kernel<<<tg, 256, 0, stream>>>(wq, wqT);
    wtrans_kernel<<<tg, 256, 0, stream>>>(wk, wkT);
    wtrans_kernel<<<tg, 256, 0, stream>>>(wv, wvT);
    wtrans_kernel<<<tg, 256, 0, stream>>>(wo, woT);

    dim3 gg(D / 128, (B * S) / 128);  // (8, 32)
    gemm_bf16<0, 0><<<gg, 256, 0, stream>>>(qb, wqT, Qh);
    gemm_bf16<0, 0><<<gg, 256, 0, stream>>>(kb, wkT, Kh);
    gemm_bf16<0, 0><<<gg, 256, 0, stream>>>(vb, wvT, Vh);

    dim3 ga(S / 128, B * H);  // (16, 32)
    attn_kernel<<<ga, 128, 0, stream>>>(Qh, Kh, Vh, attnb);

    gemm_bf16<1, 1><<<gg, 256, 0, stream>>>(attnb, woT, proj);

    ln_kernel<<<B * S, 256, 0, stream>>>(proj, q, gamma, beta, out);
}

// Round 2
// 411.212 us; speedup vs baseline: 8.7613x; 8.7613x over previous
//
#include <hip/hip_runtime.h>

// Problem constants
constexpr int B = 2, S = 2048, D = 1024, H = 16, HD = 64;
constexpr size_t BSD = (size_t)B * S * D;      // 4,194,304 elements
constexpr float SCALE = 0.125f;                 // 1/sqrt(HD)
constexpr float EPS = 1e-5f;
constexpr float NEG_BIG = -1e30f;

typedef unsigned short u16;
typedef __attribute__((ext_vector_type(8))) short bf16x8;   // 8 bf16 = 4 VGPRs
typedef __attribute__((ext_vector_type(4))) float f32x4;    // MFMA acc frag

__device__ __forceinline__ u16 f2bf(float f) {
    union { float f; unsigned u; } x; x.f = f;
    unsigned r = x.u + 0x7FFFu + ((x.u >> 16) & 1u);  // RNE
    return (u16)(r >> 16);
}

// ---------------------------------------------------------------------------
// fp32 -> bf16 elementwise cast (4 elems/thread)
// ---------------------------------------------------------------------------
__global__ void cast_bf16_kernel(const float* __restrict__ in, u16* __restrict__ out, int n4) {
    int i = blockIdx.x * blockDim.x + threadIdx.x;
    if (i < n4) {
        float4 f = ((const float4*)in)[i];
        ushort4 o;
        o.x = f2bf(f.x); o.y = f2bf(f.y); o.z = f2bf(f.z); o.w = f2bf(f.w);
        ((ushort4*)out)[i] = o;
    }
}

// ---------------------------------------------------------------------------
// W[k][n] fp32 -> Wt[n][k] bf16 (32x32 LDS tiles)
// ---------------------------------------------------------------------------
__global__ void wtrans_kernel(const float* __restrict__ W, u16* __restrict__ Wt) {
    __shared__ float t[32][33];
    int bx = blockIdx.x * 32;   // n block
    int by = blockIdx.y * 32;   // k block
    int tx = threadIdx.x & 31;
    int ty = threadIdx.x >> 5;  // 0..7
    #pragma unroll
    for (int i = 0; i < 32; i += 8)
        t[ty + i][tx] = W[(size_t)(by + ty + i) * D + bx + tx];
    __syncthreads();
    #pragma unroll
    for (int i = 0; i < 32; i += 8)
        Wt[(size_t)(bx + ty + i) * D + by + tx] = f2bf(t[tx][ty + i]);
}

// ---------------------------------------------------------------------------
// bf16 MFMA GEMM: C[M=4096][N=1024] = A[M][K=1024] * B[K][N]
//   A bf16; B given as Bt[n][k] bf16 (pre-transposed).
//   AMODE 0: A row-major [m][k]
//   AMODE 1: A is [B][H][S][HD] layout, logical [m=(b,s)][k=(h,hd)]
//   CMODE 1: fp32 row-major [m][n]            (output projection)
//   CMODE 2: bf16 scatter [bh][S][HD]         (Q, K projections)
//   CMODE 3: bf16 scatter [bh][HD][S]         (V projection, transposed)
// Tile: 128x128 per block (256 thr = 4 waves, each 64x64), BK=32.
// ---------------------------------------------------------------------------
template <int AMODE, int CMODE>
__global__ __launch_bounds__(256) void gemm_bf16(const u16* __restrict__ A,
                                                 const u16* __restrict__ Bt,
                                                 void* __restrict__ Cv) {
    constexpr int K = 1024, N = 1024;
    constexpr int LDT = 40;  // 32 + 8 pad
    __shared__ u16 As[128 * LDT];
    __shared__ u16 Bs[128 * LDT];

    const int tid = threadIdx.x;
    const int mbase = blockIdx.y * 128;
    const int nbase = blockIdx.x * 128;
    const int w = tid >> 6, lane = tid & 63;
    const int wrow = w >> 1, wcol = w & 1;
    const int quad = lane >> 4, l16 = lane & 15;

    const int sr = tid >> 1;            // staging row 0..127
    const int sc = (tid & 1) * 16;      // staging col 0 or 16

    f32x4 acc[4][4];
    #pragma unroll
    for (int i = 0; i < 4; ++i)
        #pragma unroll
        for (int j = 0; j < 4; ++j)
            acc[i][j] = (f32x4){0.f, 0.f, 0.f, 0.f};

    for (int k0 = 0; k0 < K; k0 += 32) {
        const u16* abase;
        if (AMODE == 0) {
            abase = A + (size_t)(mbase + sr) * K + k0 + sc;
        } else {
            int mm = mbase + sr;
            int b = mm >> 11, s = mm & 2047;
            int kk = k0 + sc;
            int h = kk >> 6, off = kk & 63;
            abase = A + ((((size_t)b * H + h) * S + s) * HD + off);
        }
        uint4 av0 = *(const uint4*)abase;
        uint4 av1 = *(const uint4*)(abase + 8);
        const u16* bbase = Bt + (size_t)(nbase + sr) * K + k0 + sc;
        uint4 bv0 = *(const uint4*)bbase;
        uint4 bv1 = *(const uint4*)(bbase + 8);

        __syncthreads();
        *(uint4*)&As[sr * LDT + sc] = av0;
        *(uint4*)&As[sr * LDT + sc + 8] = av1;
        *(uint4*)&Bs[sr * LDT + sc] = bv0;
        *(uint4*)&Bs[sr * LDT + sc + 8] = bv1;
        __syncthreads();

        bf16x8 af[4], bfr[4];
        #pragma unroll
        for (int i = 0; i < 4; ++i) {
            af[i] = *(const bf16x8*)&As[(wrow * 64 + i * 16 + l16) * LDT + quad * 8];
            bfr[i] = *(const bf16x8*)&Bs[(wcol * 64 + i * 16 + l16) * LDT + quad * 8];
        }
        #pragma unroll
        for (int i = 0; i < 4; ++i)
            #pragma unroll
            for (int j = 0; j < 4; ++j)
                acc[i][j] = __builtin_amdgcn_mfma_f32_16x16x32_bf16(af[i], bfr[j], acc[i][j], 0, 0, 0);
    }

    // epilogue: C layout col = lane&15 (n), row = quad*4 + reg (m)
    #pragma unroll
    for (int i = 0; i < 4; ++i) {
        int mrow0 = mbase + wrow * 64 + i * 16 + quad * 4;
        int b = mrow0 >> 11, s0 = mrow0 & 2047;
        #pragma unroll
        for (int j = 0; j < 4; ++j) {
            int n = nbase + wcol * 64 + j * 16 + l16;
            if (CMODE == 1) {
                float* C = (float*)Cv;
                #pragma unroll
                for (int r = 0; r < 4; ++r)
                    C[(size_t)(mrow0 + r) * N + n] = acc[i][j][r];
            } else if (CMODE == 2) {
                u16* C = (u16*)Cv;
                int h = n >> 6, hd = n & 63;
                #pragma unroll
                for (int r = 0; r < 4; ++r)
                    C[(((size_t)b * H + h) * S + (s0 + r)) * HD + hd] = f2bf(acc[i][j][r]);
            } else {  // CMODE 3: Vt[bh][HD][S], 4 consecutive s -> 8B store
                u16* C = (u16*)Cv;
                int h = n >> 6, hd = n & 63;
                ushort4 o;
                o.x = f2bf(acc[i][j][0]);
                o.y = f2bf(acc[i][j][1]);
                o.z = f2bf(acc[i][j][2]);
                o.w = f2bf(acc[i][j][3]);
                *(ushort4*)&C[(((size_t)b * H + h) * HD + hd) * S + s0] = o;
            }
        }
    }
}

// ---------------------------------------------------------------------------
// MFMA flash attention, causal. Block = 256 thr (4 waves), 128 q rows per
// block (32 per wave), one (b,h) per blockIdx.y. K-tiles of 128 keys.
// Q,K in [bh][S][HD] bf16; V in [bh][HD][S] bf16 (transposed).
// Per-wave private LDS region for the P C-layout -> A-frag round trip;
// no __syncthreads needed (DS ops per-wave are ordered).
// Output attnb bf16 [bh][S][HD].
// ---------------------------------------------------------------------------
__global__ __launch_bounds__(256) void fattn_kernel(const u16* __restrict__ Qb,
                                                    const u16* __restrict__ Kb,
                                                    const u16* __restrict__ Vt,
                                                    u16* __restrict__ attnb) {
    constexpr int LDP = 136;  // 128 + 8 pad (u16 elems)
    __shared__ u16 Ps[4][32][LDP];

    const int bh = blockIdx.y;
    const int qbase = blockIdx.x * 128;
    const int tid = threadIdx.x;
    const int w = tid >> 6, lane = tid & 63;
    const int quad = lane >> 4, l16 = lane & 15;
    const int qrow0 = qbase + w * 32;   // this wave's 32 q rows

    const u16* Qp = Qb + (size_t)bh * S * HD;
    const u16* Kp = Kb + (size_t)bh * S * HD;
    const u16* Vp = Vt + (size_t)bh * HD * S;

    // Q A-frags: aq[qt][h] covers rows qrow0+qt*16+(0..15), k = h*32+(0..31)
    bf16x8 aq[2][2];
    #pragma unroll
    for (int qt = 0; qt < 2; ++qt)
        #pragma unroll
        for (int h = 0; h < 2; ++h)
            aq[qt][h] = *(const bf16x8*)(Qp + (size_t)(qrow0 + qt * 16 + l16) * HD + h * 32 + quad * 8);

    f32x4 oacc[2][4];
    #pragma unroll
    for (int qt = 0; qt < 2; ++qt)
        #pragma unroll
        for (int ht = 0; ht < 4; ++ht)
            oacc[qt][ht] = (f32x4){0.f, 0.f, 0.f, 0.f};
    float mrow[2][4], lrow[2][4];
    #pragma unroll
    for (int qt = 0; qt < 2; ++qt)
        #pragma unroll
        for (int r = 0; r < 4; ++r) { mrow[qt][r] = NEG_BIG; lrow[qt][r] = 0.f; }

    const int nkt = (qbase >> 7) + 1;
    for (int kt = 0; kt < nkt; ++kt) {
        const int kb0 = kt << 7;

        // ---- scores: sc[qt][nt] = Q(16q) x K^T(16k), C layout ----
        f32x4 scv[2][8];
        #pragma unroll
        for (int nt = 0; nt < 8; ++nt) {
            const u16* kr = Kp + (size_t)(kb0 + nt * 16 + l16) * HD + quad * 8;
            bf16x8 kf0 = *(const bf16x8*)kr;
            bf16x8 kf1 = *(const bf16x8*)(kr + 32);
            #pragma unroll
            for (int qt = 0; qt < 2; ++qt) {
                f32x4 c = (f32x4){0.f, 0.f, 0.f, 0.f};
                c = __builtin_amdgcn_mfma_f32_16x16x32_bf16(aq[qt][0], kf0, c, 0, 0, 0);
                c = __builtin_amdgcn_mfma_f32_16x16x32_bf16(aq[qt][1], kf1, c, 0, 0, 0);
                scv[qt][nt] = c;
            }
        }

        // ---- causal mask on the diagonal tile ----
        if (kb0 == qbase) {
            #pragma unroll
            for (int qt = 0; qt < 2; ++qt) {
                int row = w * 32 + qt * 16 + quad * 4;  // local to qbase
                #pragma unroll
                for (int nt = 0; nt < 8; ++nt) {
                    int col = nt * 16 + l16;
                    #pragma unroll
                    for (int r = 0; r < 4; ++r)
                        if (col > row + r) scv[qt][nt][r] = NEG_BIG;
                }
            }
        }

        // ---- online softmax (per q row = per (qt, reg) per lane) ----
        #pragma unroll
        for (int qt = 0; qt < 2; ++qt) {
            float rm[4];
            #pragma unroll
            for (int r = 0; r < 4; ++r) {
                float x = scv[qt][0][r];
                #pragma unroll
                for (int nt = 1; nt < 8; ++nt) x = fmaxf(x, scv[qt][nt][r]);
                rm[r] = x;
            }
            #pragma unroll
            for (int d = 1; d < 16; d <<= 1)
                #pragma unroll
                for (int r = 0; r < 4; ++r)
                    rm[r] = fmaxf(rm[r], __shfl_xor(rm[r], d, 64));
            float alpha[4];
            #pragma unroll
            for (int r = 0; r < 4; ++r) {
                float mn = fmaxf(mrow[qt][r], rm[r] * SCALE);
                alpha[r] = __expf(mrow[qt][r] - mn);
                mrow[qt][r] = mn;
            }
            float rs[4] = {0.f, 0.f, 0.f, 0.f};
            #pragma unroll
            for (int nt = 0; nt < 8; ++nt)
                #pragma unroll
                for (int r = 0; r < 4; ++r) {
                    float p = __expf(scv[qt][nt][r] * SCALE - mrow[qt][r]);
                    scv[qt][nt][r] = p;
                    rs[r] += p;
                }
            #pragma unroll
            for (int d = 1; d < 16; d <<= 1)
                #pragma unroll
                for (int r = 0; r < 4; ++r)
                    rs[r] += __shfl_xor(rs[r], d, 64);
            #pragma unroll
            for (int r = 0; r < 4; ++r)
                lrow[qt][r] = lrow[qt][r] * alpha[r] + rs[r];
            #pragma unroll
            for (int ht = 0; ht < 4; ++ht)
                #pragma unroll
                for (int r = 0; r < 4; ++r)
                    oacc[qt][ht][r] *= alpha[r];
        }

        // ---- P (C layout) -> LDS bf16 ----
        #pragma unroll
        for (int qt = 0; qt < 2; ++qt)
            #pragma unroll
            for (int nt = 0; nt < 8; ++nt)
                #pragma unroll
                for (int r = 0; r < 4; ++r)
                    Ps[w][qt * 16 + quad * 4 + r][nt * 16 + l16] = f2bf(scv[qt][nt][r]);

        // ---- PV: O += P(32x128) x V(128x64) ----
        #pragma unroll
        for (int kk = 0; kk < 4; ++kk) {
            bf16x8 pf0 = *(const bf16x8*)&Ps[w][l16][kk * 32 + quad * 8];
            bf16x8 pf1 = *(const bf16x8*)&Ps[w][16 + l16][kk * 32 + quad * 8];
            #pragma unroll
            for (int ht = 0; ht < 4; ++ht) {
                bf16x8 vf = *(const bf16x8*)(Vp + (size_t)(ht * 16 + l16) * S + kb0 + kk * 32 + quad * 8);
                oacc[0][ht] = __builtin_amdgcn_mfma_f32_16x16x32_bf16(pf0, vf, oacc[0][ht], 0, 0, 0);
                oacc[1][ht] = __builtin_amdgcn_mfma_f32_16x16x32_bf16(pf1, vf, oacc[1][ht], 0, 0, 0);
            }
        }
    }

    // ---- epilogue: normalize, store bf16 [bh][S][HD] ----
    #pragma unroll
    for (int qt = 0; qt < 2; ++qt)
        #pragma unroll
        for (int r = 0; r < 4; ++r) {
            float inv = 1.0f / lrow[qt][r];
            int row = qrow0 + qt * 16 + quad * 4 + r;
            #pragma unroll
            for (int ht = 0; ht < 4; ++ht)
                attnb[((size_t)bh * S + row) * HD + ht * 16 + l16] = f2bf(oacc[qt][ht][r] * inv);
        }
}

// ---------------------------------------------------------------------------
// LayerNorm(proj + q) * gamma + beta  -> out (fp32). One block per row.
// ---------------------------------------------------------------------------
__global__ __launch_bounds__(256) void ln_kernel(const float* __restrict__ proj,
                                                 const float* __restrict__ qin,
                                                 const float* __restrict__ gamma,
                                                 const float* __restrict__ beta,
                                                 float* __restrict__ out) {
    const int row = blockIdx.x;
    const int t = threadIdx.x;
    const float4 p = ((const float4*)(proj + (size_t)row * D))[t];
    const float4 qq = ((const float4*)(qin + (size_t)row * D))[t];
    float v0 = p.x + qq.x, v1 = p.y + qq.y, v2 = p.z + qq.z, v3 = p.w + qq.w;
    float sum = (v0 + v1) + (v2 + v3);
    float sq = v0 * v0 + v1 * v1 + v2 * v2 + v3 * v3;
    #pragma unroll
    for (int off = 32; off > 0; off >>= 1) {
        sum += __shfl_down(sum, off, 64);
        sq  += __shfl_down(sq, off, 64);
    }
    __shared__ float s1[4], s2[4];
    if ((t & 63) == 0) { s1[t >> 6] = sum; s2[t >> 6] = sq; }
    __syncthreads();
    sum = (s1[0] + s1[1]) + (s1[2] + s1[3]);
    sq  = (s2[0] + s2[1]) + (s2[2] + s2[3]);
    const float mu = sum * (1.0f / D);
    const float var = sq * (1.0f / D) - mu * mu;
    const float rstd = rsqrtf(var + EPS);
    const float4 g = ((const float4*)gamma)[t];
    const float4 b = ((const float4*)beta)[t];
    float4 o;
    o.x = (v0 - mu) * rstd * g.x + b.x;
    o.y = (v1 - mu) * rstd * g.y + b.y;
    o.z = (v2 - mu) * rstd * g.z + b.z;
    o.w = (v3 - mu) * rstd * g.w + b.w;
    ((float4*)(out + (size_t)row * D))[t] = o;
}

// ---------------------------------------------------------------------------
extern "C" void kernel_launch(void* const* d_in, const int* in_sizes, int n_in,
                              void* d_out, int out_size, void* d_ws, size_t ws_size,
                              hipStream_t stream) {
    const float* q  = (const float*)d_in[0];
    const float* k  = (const float*)d_in[1];
    const float* v  = (const float*)d_in[2];
    const float* wq = (const float*)d_in[3];
    const float* wk = (const float*)d_in[4];
    const float* wv = (const float*)d_in[5];
    const float* wo = (const float*)d_in[6];
    const float* gamma = (const float*)d_in[7];
    const float* beta  = (const float*)d_in[8];
    // d_in[9] = mask : deterministic causal mask, applied structurally.
    float* out = (float*)d_out;

    char* ws = (char*)d_ws;
    constexpr size_t SZ_BF = BSD * 2;              // 8.39 MB
    constexpr size_t SZ_W  = (size_t)D * D * 2;    // 2.10 MB
    u16* qb  = (u16*)(ws);
    u16* kb  = (u16*)(ws + SZ_BF);
    u16* vb  = (u16*)(ws + 2 * SZ_BF);
    u16* wqT = (u16*)(ws + 3 * SZ_BF);
    u16* wkT = (u16*)(ws + 3 * SZ_BF + SZ_W);
    u16* wvT = (u16*)(ws + 3 * SZ_BF + 2 * SZ_W);
    u16* woT = (u16*)(ws + 3 * SZ_BF + 3 * SZ_W);
    u16* Qh   = (u16*)(ws + 3 * SZ_BF + 4 * SZ_W);
    u16* Kh   = (u16*)(ws + 4 * SZ_BF + 4 * SZ_W);
    u16* Vth  = (u16*)(ws + 5 * SZ_BF + 4 * SZ_W);
    u16* attnb = (u16*)(ws + 6 * SZ_BF + 4 * SZ_W);
    float* proj = (float*)(ws + 7 * SZ_BF + 4 * SZ_W);

    const int n4 = (int)(BSD / 4);
    cast_bf16_kernel<<<n4 / 256, 256, 0, stream>>>(q, qb, n4);
    cast_bf16_kernel<<<n4 / 256, 256, 0, stream>>>(k, kb, n4);
    cast_bf16_kernel<<<n4 / 256, 256, 0, stream>>>(v, vb, n4);

    dim3 tg(32, 32);
    wtrans_kernel<<<tg, 256, 0, stream>>>(wq, wqT);
    wtrans_kernel<<<tg, 256, 0, stream>>>(wk, wkT);
    wtrans_kernel<<<tg, 256, 0, stream>>>(wv, wvT);
    wtrans_kernel<<<tg, 256, 0, stream>>>(wo, woT);

    dim3 gg(D / 128, (B * S) / 128);  // (8, 32)
    gemm_bf16<0, 2><<<gg, 256, 0, stream>>>(qb, wqT, Qh);
    gemm_bf16<0, 2><<<gg, 256, 0, stream>>>(kb, wkT, Kh);
    gemm_bf16<0, 3><<<gg, 256, 0, stream>>>(vb, wvT, Vth);

    dim3 ga(S / 128, B * H);  // (16, 32)
    fattn_kernel<<<ga, 256, 0, stream>>>(Qh, Kh, Vth, attnb);

    gemm_bf16<1, 1><<<gg, 256, 0, stream>>>(attnb, woT, proj);

    ln_kernel<<<B * S, 256, 0, stream>>>(proj, q, gamma, beta, out);
}